// Round 1
// 413.783 us; speedup vs baseline: 1.0097x; 1.0097x over previous
//
#include <hip/hip_runtime.h>
#include <math.h>

#define TOK 4096
#define DM 2048
#define DQ 682
#define DQP 704
#define DKV 1024
#define DUKV 3072
#define NH 16
#define T_SEQ 2048
#define NQKV 1792   // 704 (padded Wdq) + 1088 (Wdkv)

typedef __attribute__((ext_vector_type(8))) short short8;
typedef __attribute__((ext_vector_type(4))) float floatx4;
typedef __attribute__((ext_vector_type(2))) unsigned int uint2v;

__device__ __forceinline__ unsigned short f2bf(float f) {
  union { float f; unsigned int u; } v; v.f = f;
  unsigned int u = v.u;
  u += 0x7fffu + ((u >> 16) & 1u);
  return (unsigned short)(u >> 16);
}
__device__ __forceinline__ unsigned short f2bf_fast(float f) {
  union { float f; unsigned int u; } v; v.f = f;
  return (unsigned short)((v.u + 0x8000u) >> 16);
}

typedef __attribute__((address_space(1))) const unsigned int as1_u32;
typedef __attribute__((address_space(3))) unsigned int as3_u32;
__device__ __forceinline__ void async16(const void* g, void* l) {
  __builtin_amdgcn_global_load_lds((as1_u32*)g, (as3_u32*)l, 16, 0, 0);
}

// ---------------------------------------------------------------------------
// Split-K c_qkv GEMM (dbuf, BK=32): z=0/1 computes K-half into P0/P1 (fp32,
// no bias — bias added in the reduce). lda/ldb=2048, ldc=1792, all cols valid.
// 896 blocks -> 3.5 blocks/CU co-resident to cover HBM prefetch latency.
// ---------------------------------------------------------------------------
__global__ __launch_bounds__(256) void gemm_dqkv_sk(
    const unsigned short* __restrict__ A,
    const unsigned short* __restrict__ B,
    float* __restrict__ P0, float* __restrict__ P1)
{
  __shared__ __align__(16) unsigned short sm[16384];
  const int kz = blockIdx.z;
  const unsigned short* Ab = A + kz * 1024;
  const unsigned short* Bb = B + kz * 1024;
  float* C = kz ? P1 : P0;
  const int K = 1024;

  const int tid = threadIdx.x;
  const int w = tid >> 6, lane = tid & 63, q = lane >> 4, r = lane & 15;
  const int bm = blockIdx.y * 128, bn = blockIdx.x * 128;

  floatx4 acc[4][4];
#pragma unroll
  for (int i = 0; i < 4; i++)
#pragma unroll
    for (int j = 0; j < 4; j++) acc[i][j] = (floatx4){0.f, 0.f, 0.f, 0.f};

  const int srow = tid >> 2, scol = (tid & 3) * 8;
  const unsigned short* Ag0 = Ab + (size_t)(bm + srow) * 2048 + scol;
  const unsigned short* Ag1 = Ab + (size_t)(bm + 64 + srow) * 2048 + scol;
  const unsigned short* Bg0 = Bb + (size_t)(bn + srow) * 2048 + scol;
  const unsigned short* Bg1 = Bb + (size_t)(bn + 64 + srow) * 2048 + scol;
  const int mrow0 = (w >> 1) * 64, ncol0 = (w & 1) * 64;

  async16(Ag0, &sm[w * 512]);
  async16(Ag1, &sm[2048 + w * 512]);
  async16(Bg0, &sm[8192 + w * 512]);
  async16(Bg1, &sm[8192 + 2048 + w * 512]);

  for (int k0 = 0; k0 < K; k0 += 32) {
    const int cur = (k0 >> 5) & 1;
    __syncthreads();
    if (k0 + 32 < K) {
      const int nxt = cur ^ 1;
      async16(Ag0 + k0 + 32, &sm[nxt * 4096 + w * 512]);
      async16(Ag1 + k0 + 32, &sm[nxt * 4096 + 2048 + w * 512]);
      async16(Bg0 + k0 + 32, &sm[8192 + nxt * 4096 + w * 512]);
      async16(Bg1 + k0 + 32, &sm[8192 + nxt * 4096 + 2048 + w * 512]);
    }
    const unsigned short* As = &sm[cur * 4096];
    const unsigned short* Bs = &sm[8192 + cur * 4096];
    short8 a[4], b[4];
#pragma unroll
    for (int i = 0; i < 4; i++)
      a[i] = *(const short8*)&As[(mrow0 + i * 16 + r) * 32 + q * 8];
#pragma unroll
    for (int j = 0; j < 4; j++)
      b[j] = *(const short8*)&Bs[(ncol0 + j * 16 + r) * 32 + q * 8];
#pragma unroll
    for (int i = 0; i < 4; i++)
#pragma unroll
      for (int j = 0; j < 4; j++)
        acc[i][j] = __builtin_amdgcn_mfma_f32_16x16x32_bf16(a[i], b[j], acc[i][j], 0, 0, 0);
  }

#pragma unroll
  for (int j = 0; j < 4; j++) {
    int gc = bn + ncol0 + j * 16 + r;
#pragma unroll
    for (int i = 0; i < 4; i++) {
#pragma unroll
      for (int v = 0; v < 4; v++) {
        int gr = bm + mrow0 + i * 16 + q * 4 + v;
        C[(size_t)gr * NQKV + gc] = acc[i][j][v];
      }
    }
  }
}

// ---------------------------------------------------------------------------
// Wo GEMM, BK=64 dbuf: LDS image chunked [c2][128][32] (identical bank-safe
// addressing to BK=32, doubled). 64 KB LDS, 2 blocks/CU (grid 512 = exact).
// Halves barrier count; doubles compute per barrier window.
// ---------------------------------------------------------------------------
__global__ __launch_bounds__(256) void gemm_wo64(
    const unsigned short* __restrict__ A,
    const unsigned short* __restrict__ B,
    const float* __restrict__ bias, float* __restrict__ C)
{
  __shared__ __align__(16) unsigned short sm[32768]; // A:2x8192 @0, B:@16384
  const int tid = threadIdx.x;
  const int w = tid >> 6, lane = tid & 63, q = lane >> 4, r = lane & 15;
  const int bm = blockIdx.y * 128, bn = blockIdx.x * 128;

  floatx4 acc[4][4];
#pragma unroll
  for (int i = 0; i < 4; i++)
#pragma unroll
    for (int j = 0; j < 4; j++) acc[i][j] = (floatx4){0.f, 0.f, 0.f, 0.f};

  const int srow = tid >> 2, scol = (tid & 3) * 8;
  const unsigned short* Ag0 = A + (size_t)(bm + srow) * 2048 + scol;
  const unsigned short* Ag1 = A + (size_t)(bm + 64 + srow) * 2048 + scol;
  const unsigned short* Bg0 = B + (size_t)(bn + srow) * 2048 + scol;
  const unsigned short* Bg1 = B + (size_t)(bn + 64 + srow) * 2048 + scol;
  const int mrow0 = (w >> 1) * 64, ncol0 = (w & 1) * 64;

#pragma unroll
  for (int c2 = 0; c2 < 2; c2++) {
    async16(Ag0 + c2 * 32, &sm[c2 * 4096 + w * 512]);
    async16(Ag1 + c2 * 32, &sm[c2 * 4096 + 2048 + w * 512]);
    async16(Bg0 + c2 * 32, &sm[16384 + c2 * 4096 + w * 512]);
    async16(Bg1 + c2 * 32, &sm[16384 + c2 * 4096 + 2048 + w * 512]);
  }

  for (int k0 = 0; k0 < 2048; k0 += 64) {
    const int cur = (k0 >> 6) & 1;
    __syncthreads();
    if (k0 + 64 < 2048) {
      const int nxt = cur ^ 1;
#pragma unroll
      for (int c2 = 0; c2 < 2; c2++) {
        async16(Ag0 + k0 + 64 + c2 * 32, &sm[nxt * 8192 + c2 * 4096 + w * 512]);
        async16(Ag1 + k0 + 64 + c2 * 32, &sm[nxt * 8192 + c2 * 4096 + 2048 + w * 512]);
        async16(Bg0 + k0 + 64 + c2 * 32, &sm[16384 + nxt * 8192 + c2 * 4096 + w * 512]);
        async16(Bg1 + k0 + 64 + c2 * 32, &sm[16384 + nxt * 8192 + c2 * 4096 + 2048 + w * 512]);
      }
    }
#pragma unroll
    for (int c2 = 0; c2 < 2; c2++) {
      const unsigned short* As = &sm[cur * 8192 + c2 * 4096];
      const unsigned short* Bs = &sm[16384 + cur * 8192 + c2 * 4096];
      short8 a[4], b[4];
#pragma unroll
      for (int i = 0; i < 4; i++)
        a[i] = *(const short8*)&As[(mrow0 + i * 16 + r) * 32 + q * 8];
#pragma unroll
      for (int j = 0; j < 4; j++)
        b[j] = *(const short8*)&Bs[(ncol0 + j * 16 + r) * 32 + q * 8];
#pragma unroll
      for (int i = 0; i < 4; i++)
#pragma unroll
        for (int j = 0; j < 4; j++)
          acc[i][j] = __builtin_amdgcn_mfma_f32_16x16x32_bf16(a[i], b[j], acc[i][j], 0, 0, 0);
    }
  }

#pragma unroll
  for (int j = 0; j < 4; j++) {
    int gc = bn + ncol0 + j * 16 + r;
    float bv = bias[gc];
#pragma unroll
    for (int i = 0; i < 4; i++) {
#pragma unroll
      for (int v = 0; v < 4; v++) {
        int gr = bm + mrow0 + i * 16 + q * 4 + v;
        C[(size_t)gr * 2048 + gc] = acc[i][j][v] + bv;
      }
    }
  }
}

// ---------------------------------------------------------------------------
// Fused up-projections (dbuf, R10-verified):
//  bx <  16: q-up, fused rotary+scale -> Q_all bf16 (h = bx)
//  bx >= 16: kv-up -> direct tile writes: Kn_blk (dd<64), V_blk (dd>=64)
// ---------------------------------------------------------------------------
__global__ __launch_bounds__(256) void gemm_up_fused(
    const unsigned short* __restrict__ Aq, const unsigned short* __restrict__ Bq,
    const float* __restrict__ biasq, unsigned short* __restrict__ Qall,
    const unsigned short* __restrict__ Akv, const unsigned short* __restrict__ Bkv,
    const float* __restrict__ biaskv,
    unsigned short* __restrict__ Kn, unsigned short* __restrict__ Vb)
{
  __shared__ __align__(16) unsigned short sm[16384];
  const int tid = threadIdx.x;
  const int w = tid >> 6, lane = tid & 63, q = lane >> 4, r = lane & 15;
  const int bx = blockIdx.x;
  const bool isQ = bx < 16;
  const int bn = isQ ? bx * 128 : (bx - 16) * 128;
  const int bm = blockIdx.y * 128;
  const int K = isQ ? DQP : DKV;
  const unsigned short* A = isQ ? Aq : Akv;
  const unsigned short* B = isQ ? Bq : Bkv;

  floatx4 acc[4][4];
#pragma unroll
  for (int i = 0; i < 4; i++)
#pragma unroll
    for (int j = 0; j < 4; j++) acc[i][j] = (floatx4){0.f, 0.f, 0.f, 0.f};

  const int srow = tid >> 2, scol = (tid & 3) * 8;
  const unsigned short* Ag0 = A + (size_t)(bm + srow) * K + scol;
  const unsigned short* Ag1 = A + (size_t)(bm + 64 + srow) * K + scol;
  const unsigned short* Bg0 = B + (size_t)(bn + srow) * K + scol;
  const unsigned short* Bg1 = B + (size_t)(bn + 64 + srow) * K + scol;
  const int mrow0 = (w >> 1) * 64, ncol0 = (w & 1) * 64;

  async16(Ag0, &sm[w * 512]);
  async16(Ag1, &sm[2048 + w * 512]);
  async16(Bg0, &sm[8192 + w * 512]);
  async16(Bg1, &sm[8192 + 2048 + w * 512]);

  for (int k0 = 0; k0 < K; k0 += 32) {
    const int cur = (k0 >> 5) & 1;
    __syncthreads();
    if (k0 + 32 < K) {
      const int nxt = cur ^ 1;
      async16(Ag0 + k0 + 32, &sm[nxt * 4096 + w * 512]);
      async16(Ag1 + k0 + 32, &sm[nxt * 4096 + 2048 + w * 512]);
      async16(Bg0 + k0 + 32, &sm[8192 + nxt * 4096 + w * 512]);
      async16(Bg1 + k0 + 32, &sm[8192 + nxt * 4096 + 2048 + w * 512]);
    }
    const unsigned short* As = &sm[cur * 4096];
    const unsigned short* Bs = &sm[8192 + cur * 4096];
    short8 a[4], b[4];
#pragma unroll
    for (int i = 0; i < 4; i++)
      a[i] = *(const short8*)&As[(mrow0 + i * 16 + r) * 32 + q * 8];
#pragma unroll
    for (int j = 0; j < 4; j++)
      b[j] = *(const short8*)&Bs[(ncol0 + j * 16 + r) * 32 + q * 8];
#pragma unroll
    for (int i = 0; i < 4; i++)
#pragma unroll
      for (int j = 0; j < 4; j++)
        acc[i][j] = __builtin_amdgcn_mfma_f32_16x16x32_bf16(a[i], b[j], acc[i][j], 0, 0, 0);
  }

  if (!isQ) {
#pragma unroll
    for (int j = 0; j < 4; j++) {
      int gc = bn + ncol0 + j * 16 + r;
      float bv = biaskv[gc];
      int hh = gc / 192;
      int rel = gc - hh * 192;
#pragma unroll
      for (int i = 0; i < 4; i++) {
#pragma unroll
        for (int v = 0; v < 4; v++) {
          int gr = bm + mrow0 + i * 16 + q * 4 + v;
          int bb = gr >> 11, tt = gr & 2047;
          int bhh = bb * NH + hh;
          int kt = tt >> 6;
          unsigned short val = f2bf(acc[i][j][v] + bv);
          if (rel < 64) {
            Kn[((size_t)(bhh * 32 + kt)) * 4096 + (rel >> 5) * 2048 +
               (tt & 63) * 32 + (rel & 31)] = val;
          } else {
            int d = rel - 64;
            Vb[((size_t)(bhh * 32 + kt)) * 8192 + ((tt >> 5) & 1) * 4096 +
               d * 32 + (tt & 31)] = val;
          }
        }
      }
    }
    return;
  }

  const int h = bx;
  const float QS = (float)(0.08838834764831845 * 1.4426950408889634);
  if ((w & 1) == 0) {
#pragma unroll
    for (int j = 0; j < 4; j++) {
      int d = j * 16 + r;
      float bv = biasq[h * 128 + d];
#pragma unroll
      for (int i = 0; i < 4; i++) {
#pragma unroll
        for (int v = 0; v < 4; v++) {
          int gr = bm + mrow0 + i * 16 + q * 4 + v;
          int bb = gr >> 11, t = gr & 2047;
          Qall[(((size_t)(bb * NH + h)) * T_SEQ + t) * 128 + d] =
              f2bf((acc[i][j][v] + bv) * QS);
        }
      }
    }
  } else {
    float cs[2], sn[2], bv1[2], bv2[2];
#pragma unroll
    for (int jp = 0; jp < 2; jp++) {
      int jj = jp * 16 + r;
      float ang = (float)h * exp2f(-(float)jj * (13.287712379549449f / 32.0f));
      cs[jp] = cosf(ang); sn[jp] = sinf(ang);
      bv1[jp] = biasq[h * 128 + 64 + jj];
      bv2[jp] = biasq[h * 128 + 96 + jj];
    }
#pragma unroll
    for (int i = 0; i < 4; i++) {
#pragma unroll
      for (int v = 0; v < 4; v++) {
        int gr = bm + mrow0 + i * 16 + q * 4 + v;
        int bb = gr >> 11, t = gr & 2047;
        unsigned short* Qr = Qall + (((size_t)(bb * NH + h)) * T_SEQ + t) * 128;
#pragma unroll
        for (int jp = 0; jp < 2; jp++) {
          int jj = jp * 16 + r;
          float x1 = acc[i][jp][v] + bv1[jp];
          float x2 = acc[i][jp + 2][v] + bv2[jp];
          Qr[64 + jj] = f2bf((x1 * cs[jp] + x2 * sn[jp]) * QS);
          Qr[96 + jj] = f2bf((x2 * cs[jp] - x1 * sn[jp]) * QS);
        }
      }
    }
  }
}

// ---------------------------------------------------------------------------
// One prep launch: x cvt + 5 weight cvts + bias concat (block-range dispatch).
// ---------------------------------------------------------------------------
__device__ __forceinline__ void cvt_region(
    const float* __restrict__ in, unsigned short* __restrict__ out,
    int irows, int icols, int ocols, long idx)
{
  int rr = (int)(idx / ocols);
  int cc = (int)(idx - (long)rr * ocols);
  out[idx] = (rr < irows && cc < icols) ? f2bf(in[(size_t)rr * icols + cc]) : 0;
}

__global__ __launch_bounds__(256) void prep_all(
    const float* __restrict__ x,
    const float* __restrict__ Wdq_w, const float* __restrict__ Wdkv_w,
    const float* __restrict__ Wuq_w, const float* __restrict__ Wukv_w,
    const float* __restrict__ Wo_w,
    const float* __restrict__ Wdq_b, const float* __restrict__ Wdkv_b,
    unsigned short* __restrict__ x_bf,
    unsigned short* __restrict__ Wqkv_bf, unsigned short* __restrict__ Wuq_bf,
    unsigned short* __restrict__ Wukv_bf, unsigned short* __restrict__ Wo_bf,
    float* __restrict__ bias_qkv)
{
  const long bx = blockIdx.x;
  if (bx < 32768) {
    long idx = bx * 256 + threadIdx.x;
    x_bf[idx] = f2bf(x[idx]);
  } else if (bx < 38400) {
    cvt_region(Wdq_w, Wqkv_bf, 682, 2048, 2048, (bx - 32768) * 256 + threadIdx.x);
  } else if (bx < 47104) {
    cvt_region(Wdkv_w, Wqkv_bf + 704L * 2048, 1088, 2048, 2048,
               (bx - 38400) * 256 + threadIdx.x);
  } else if (bx < 52736) {
    cvt_region(Wuq_w, Wuq_bf, 2048, 682, 704, (bx - 47104) * 256 + threadIdx.x);
  } else if (bx < 65024) {
    cvt_region(Wukv_w, Wukv_bf, 3072, 1024, 1024, (bx - 52736) * 256 + threadIdx.x);
  } else if (bx < 81408) {
    cvt_region(Wo_w, Wo_bf, 2048, 2048, 2048, (bx - 65024) * 256 + threadIdx.x);
  } else {
    int i = (int)(bx - 81408) * 256 + threadIdx.x;
    if (i < NQKV)
      bias_qkv[i] = (i < DQ) ? Wdq_b[i] : ((i < DQP) ? 0.f : Wdkv_b[i - DQP]);
  }
}

// ---------------------------------------------------------------------------
// ln_dual_r: reduce split-K partials (p0+p1+bias) + LayerNorm (single-pass
// sum/sumsq, 2 read-passes) for q rows [0,4096) and kv rows [4096,8192);
// blocks >= 8192 sum+convert rope cols [1728,1792) into Kr_blk tile layout.
// ---------------------------------------------------------------------------
__global__ __launch_bounds__(256) void ln_dual_r(
    const float* __restrict__ p0, const float* __restrict__ p1,
    const float* __restrict__ bqkv,
    unsigned short* __restrict__ outq, unsigned short* __restrict__ outkv,
    unsigned short* __restrict__ Kr,
    const float* __restrict__ qg, const float* __restrict__ qb2,
    const float* __restrict__ kg, const float* __restrict__ kb2)
{
  __shared__ float sbuf[8];
  const int blk = blockIdx.x;
  if (blk >= 8192) {
    const int base = (blk - 8192) * 512;
#pragma unroll
    for (int s = 0; s < 2; s++) {
      int idx = base + s * 256 + threadIdx.x;
      int row = idx >> 6, dr = idx & 63;
      size_t off = (size_t)row * NQKV + 1728 + dr;
      float v = p0[off] + p1[off] + bqkv[1728 + dr];
      Kr[((size_t)((row >> 11) * 32 + ((row & 2047) >> 6))) * 4096 +
         (dr >> 5) * 2048 + (row & 63) * 32 + (dr & 31)] = f2bf(v);
    }
    return;
  }
  const bool isQ = blk < 4096;
  const int r2 = isQ ? blk : blk - 4096;
  const int off = isQ ? 0 : DQP;
  const float* x0 = p0 + (size_t)r2 * NQKV + off;
  const float* x1 = p1 + (size_t)r2 * NQKV + off;
  const float* bb = bqkv + off;
  const int D = isQ ? DQ : DKV;
  const int ocols = isQ ? DQP : DKV;
  const float* g = isQ ? qg : kg;
  const float* bta = isQ ? qb2 : kb2;
  unsigned short* orow = (isQ ? outq : outkv) + (size_t)r2 * ocols;

  float s = 0.f, s2 = 0.f;
  for (int i = threadIdx.x; i < D; i += 256) {
    float v = x0[i] + x1[i] + bb[i];
    s += v; s2 += v * v;
  }
#pragma unroll
  for (int o = 32; o > 0; o >>= 1) {
    s += __shfl_down(s, o, 64);
    s2 += __shfl_down(s2, o, 64);
  }
  int wid = threadIdx.x >> 6;
  __syncthreads();
  if ((threadIdx.x & 63) == 0) { sbuf[wid] = s; sbuf[4 + wid] = s2; }
  __syncthreads();
  float su = sbuf[0] + sbuf[1] + sbuf[2] + sbuf[3];
  float sq = sbuf[4] + sbuf[5] + sbuf[6] + sbuf[7];
  float mu = su / (float)D;
  float var = sq / (float)D - mu * mu;
  float rstd = rsqrtf(var + 1e-5f);
  for (int i = threadIdx.x; i < ocols; i += 256) {
    float v = (i < D) ? ((x0[i] + x1[i] + bb[i]) - mu) * rstd * g[i] + bta[i] : 0.f;
    orow[i] = (i < D) ? f2bf(v) : 0;
  }
}

// ---------------------------------------------------------------------------
// attn v5: balanced-pair flash attention. 64-row q-tiles (32 total); block
// `pr` serially processes tile a=pr then a=31-pr -> EVERY block does exactly
// 33 kt-iterations (vs 2..32 imbalance in v4). Each wave owns 16 q-rows.
// Same LDS dbuf layout, S^T-form MFMA, in-register softmax as v4.
// Same-bh blocks share an XCD (id%8 == bhid%8) for K/V L2 locality.
// ---------------------------------------------------------------------------
__global__ __launch_bounds__(256, 2) void attn_mfma5(
    const unsigned short* __restrict__ Qall,
    const unsigned short* __restrict__ Kn,
    const unsigned short* __restrict__ Kr,
    const unsigned short* __restrict__ Vb,
    unsigned short* __restrict__ y)
{
  __shared__ __align__(16) unsigned short sm[37376];
  const int id = (int)blockIdx.x;
  const int bhid = id & 31;
  const int pr = id >> 5;           // 0..15 : pair index
  const int h = bhid & 15, b = bhid >> 4;
  const int tid = threadIdx.x;
  const int w = tid >> 6, lane = tid & 63, q = lane >> 4, r = lane & 15;
  const int bh = bhid;

  const char* KnG = (const char*)(Kn + (size_t)bh * 32 * 4096);
  const char* KrG = (const char*)(Kr + (size_t)b * 32 * 4096);
  const char* VG  = (const char*)(Vb + (size_t)bh * 32 * 8192);
  char* smB = (char*)sm;
  unsigned short* Psw = sm + 32768 + w * 1152;

#define PREFETCH_KV(kt_, buf_)                                                 \
  {                                                                            \
    const char* kn_ = KnG + (size_t)(kt_) * 8192;                              \
    const char* kr_ = KrG + (size_t)(kt_) * 8192;                              \
    const char* vg_ = VG + (size_t)(kt_) * 16384;                              \
    char* kd_ = smB + (buf_) * 16384;                                          \
    char* vd_ = smB + 32768 + (buf_) * 16384;                                  \
    _Pragma("unroll")                                                          \
    for (int i_ = 0; i_ < 2; i_++) {                                           \
      async16(kn_ + i_ * 4096 + w * 1024 + lane * 16,                          \
              kd_ + i_ * 4096 + w * 1024);                                     \
      async16(kr_ + i_ * 4096 + w * 1024 + lane * 16,                          \
              kd_ + 8192 + i_ * 4096 + w * 1024);                              \
    }                                                                          \
    _Pragma("unroll")                                                          \
    for (int i_ = 0; i_ < 4; i_++)                                             \
      async16(vg_ + i_ * 4096 + w * 1024 + lane * 16,                          \
              vd_ + i_ * 4096 + w * 1024);                                     \
  }

  for (int seg = 0; seg < 2; seg++) {
    const int a = seg ? (31 - pr) : pr;   // q-tile index, rows [a*64, a*64+64)
    if (seg) __syncthreads();             // all reads of prev segment done
    PREFETCH_KV(0, 0);

    // Q fragment for this wave's 16 rows: [a*64 + w*16 + r]
    short8 qb[4];
    const unsigned short* Qrow =
        Qall + ((size_t)bh * T_SEQ + (size_t)a * 64 + w * 16 + r) * 128 + q * 8;
#pragma unroll
    for (int c = 0; c < 4; c++) qb[c] = *(const short8*)(Qrow + c * 32);

    floatx4 oacc[8];
#pragma unroll
    for (int jd = 0; jd < 8; jd++) oacc[jd] = (floatx4){0.f, 0.f, 0.f, 0.f};
    float m_i = -3.0e38f, l_i = 0.f;

    for (int kt = 0; kt <= a; kt++) {
      const int cur = kt & 1;
      __syncthreads();
      if (kt < a) PREFETCH_KV(kt + 1, cur ^ 1);

      const unsigned short* KsC = sm + cur * 8192;
      const unsigned short* VsC = sm + 16384 + cur * 8192;

      floatx4 sacc[4];
#pragma unroll
      for (int j = 0; j < 4; j++) sacc[j] = (floatx4){0.f, 0.f, 0.f, 0.f};
#pragma unroll
      for (int c = 0; c < 4; c++) {
        short8 ak[4];
#pragma unroll
        for (int j = 0; j < 4; j++)
          ak[j] = *(const short8*)&KsC[c * 2048 + (j * 16 + r) * 32 + q * 8];
#pragma unroll
        for (int j = 0; j < 4; j++)
          sacc[j] = __builtin_amdgcn_mfma_f32_16x16x32_bf16(ak[j], qb[c], sacc[j], 0, 0, 0);
      }

      float sv[16];
#pragma unroll
      for (int j = 0; j < 4; j++)
#pragma unroll
        for (int v = 0; v < 4; v++) sv[j * 4 + v] = sacc[j][v];
      const int rel = (a - kt) * 64 + w * 16 + r;
      if (rel < 63) {
#pragma unroll
        for (int j = 0; j < 4; j++)
#pragma unroll
          for (int v = 0; v < 4; v++)
            if (j * 16 + q * 4 + v > rel) sv[j * 4 + v] = -3.0e38f;
      }
      float rm = sv[0];
#pragma unroll
      for (int t16 = 1; t16 < 16; t16++) rm = fmaxf(rm, sv[t16]);
      rm = fmaxf(rm, __shfl_xor(rm, 16, 64));
      rm = fmaxf(rm, __shfl_xor(rm, 32, 64));
      float mnew = fmaxf(m_i, rm);
      float alpha = exp2f(m_i - mnew);
      m_i = mnew;
      float p[16], rsum = 0.f;
#pragma unroll
      for (int t16 = 0; t16 < 16; t16++) { p[t16] = exp2f(sv[t16] - mnew); rsum += p[t16]; }
      rsum += __shfl_xor(rsum, 16, 64);
      rsum += __shfl_xor(rsum, 32, 64);
      l_i = l_i * alpha + rsum;
#pragma unroll
      for (int jd = 0; jd < 8; jd++) {
        oacc[jd][0] *= alpha; oacc[jd][1] *= alpha;
        oacc[jd][2] *= alpha; oacc[jd][3] *= alpha;
      }
#pragma unroll
      for (int j = 0; j < 4; j++) {
        unsigned int lo = (unsigned int)f2bf_fast(p[j * 4 + 0]) |
                          ((unsigned int)f2bf_fast(p[j * 4 + 1]) << 16);
        unsigned int hi = (unsigned int)f2bf_fast(p[j * 4 + 2]) |
                          ((unsigned int)f2bf_fast(p[j * 4 + 3]) << 16);
        uint2v pk; pk[0] = lo; pk[1] = hi;
        *(uint2v*)&Psw[r * 72 + j * 16 + q * 4] = pk;
      }
#pragma unroll
      for (int c2 = 0; c2 < 2; c2++) {
        short8 pb = *(const short8*)&Psw[r * 72 + c2 * 32 + q * 8];
#pragma unroll
        for (int jd = 0; jd < 8; jd++) {
          short8 bv = *(const short8*)&VsC[c2 * 4096 + (jd * 16 + r) * 32 + q * 8];
          oacc[jd] = __builtin_amdgcn_mfma_f32_16x16x32_bf16(bv, pb, oacc[jd], 0, 0, 0);
        }
      }
    }

    float inv = 1.0f / l_i;
    unsigned short* yr =
        y + ((size_t)(b * T_SEQ) + (size_t)a * 64 + w * 16 + r) * DM + h * 128;
#pragma unroll
    for (int jd = 0; jd < 8; jd++) {
      unsigned short o0 = f2bf(oacc[jd][0] * inv);
      unsigned short o1 = f2bf(oacc[jd][1] * inv);
      unsigned short o2 = f2bf(oacc[jd][2] * inv);
      unsigned short o3 = f2bf(oacc[jd][3] * inv);
      unsigned int lo = (unsigned int)o0 | ((unsigned int)o1 << 16);
      unsigned int hi = (unsigned int)o2 | ((unsigned int)o3 << 16);
      unsigned int* dst = (unsigned int*)(yr + jd * 16 + q * 4);
      dst[0] = lo; dst[1] = hi;
    }
  }
#undef PREFETCH_KV
}

// ---------------------------------------------------------------------------
extern "C" void kernel_launch(void* const* d_in, const int* in_sizes, int n_in,
                              void* d_out, int out_size, void* d_ws, size_t ws_size,
                              hipStream_t stream) {
  const float* x      = (const float*)d_in[0];
  const float* Wdq_w  = (const float*)d_in[1];
  const float* Wdq_b  = (const float*)d_in[2];
  const float* qn_g   = (const float*)d_in[3];
  const float* qn_b   = (const float*)d_in[4];
  const float* Wuq_w  = (const float*)d_in[5];
  const float* Wuq_b  = (const float*)d_in[6];
  const float* Wdkv_w = (const float*)d_in[7];
  const float* Wdkv_b = (const float*)d_in[8];
  const float* kvn_g  = (const float*)d_in[9];
  const float* kvn_b  = (const float*)d_in[10];
  const float* Wukv_w = (const float*)d_in[11];
  const float* Wukv_b = (const float*)d_in[12];
  const float* Wo_w   = (const float*)d_in[13];
  const float* Wo_b   = (const float*)d_in[14];
  float* out = (float*)d_out;

  float* ws = (float*)d_ws;
  unsigned short* x_bf    = (unsigned short*)(ws);              // dies after dqkv gemm
  unsigned short* y_bf    = (unsigned short*)(ws);              // alias: attn output
  unsigned short* Wqkv_bf = (unsigned short*)(ws + 4194304);    // 1792x2048
  unsigned short* Wuq_bf  = (unsigned short*)(ws + 6029312);    // 2048x704
  unsigned short* Wukv_bf = (unsigned short*)(ws + 6750208);    // 3072x1024
  float* bias_qkv = ws + 8323072;                               // 1792
  float* p0       = ws + 8324864;                               // 4096x1792 fp32
  float* p1       = ws + 15664896;                              // 4096x1792 fp32
  unsigned short* c_q_bf = (unsigned short*)(ws + 23004928);    // 4096x704
  unsigned short* kvn_bf = (unsigned short*)(ws + 24446720);    // 4096x1024
  unsigned short* Q_all  = (unsigned short*)(ws + 26543872);    // 2x16x2048x128
  unsigned short* Kn_blk = (unsigned short*)(ws + 30738176);    // 32bh x 32kt x 4096
  unsigned short* Kr_blk = (unsigned short*)(ws + 32835328);    // 2b x 32kt x 4096
  unsigned short* V_blk  = (unsigned short*)(ws + 32966400);    // 32bh x 32kt x 8192
  unsigned short* Wo_bf  = (unsigned short*)(ws + 37160704);    // 2048x2048

  dim3 blk(256);

  // one prep launch: x cvt + weights + bias concat
  prep_all<<<81415, blk, 0, stream>>>(x, Wdq_w, Wdkv_w, Wuq_w, Wukv_w, Wo_w,
                                      Wdq_b, Wdkv_b,
                                      x_bf, Wqkv_bf, Wuq_bf, Wukv_bf, Wo_bf,
                                      bias_qkv);
  // split-K c_qkv partials (896 blocks)
  gemm_dqkv_sk<<<dim3(14, 32, 2), blk, 0, stream>>>(x_bf, Wqkv_bf, p0, p1);
  // reduce + dual LN + rope->Kr_blk
  ln_dual_r<<<8704, blk, 0, stream>>>(p0, p1, bias_qkv, c_q_bf, kvn_bf, Kr_blk,
                                      qn_g, qn_b, kvn_g, kvn_b);
  // fused up-projections: qrope -> Q_all ; kv -> Kn_blk / V_blk
  gemm_up_fused<<<dim3(40, 32), blk, 0, stream>>>(c_q_bf, Wuq_bf, Wuq_b, Q_all,
                                                  kvn_bf, Wukv_bf, Wukv_b,
                                                  Kn_blk, V_blk);
  // attention: balanced-pair schedule, 512 blocks (2/CU), 33 iters/block
  attn_mfma5<<<512, blk, 0, stream>>>(Q_all, Kn_blk, Kr_blk, V_blk, y_bf);
  // out = y @ Wo^T + b (BK=64 dbuf)
  gemm_wo64<<<dim3(16, 32), blk, 0, stream>>>(y_bf, Wo_bf, Wo_b, out);
}

// Round 2
// 396.068 us; speedup vs baseline: 1.0549x; 1.0447x over previous
//
#include <hip/hip_runtime.h>
#include <math.h>

#define TOK 4096
#define DM 2048
#define DQ 682
#define DQP 704
#define DKV 1024
#define DUKV 3072
#define NH 16
#define T_SEQ 2048
#define NQKV 1792   // 704 (padded Wdq) + 1088 (Wdkv)

typedef __attribute__((ext_vector_type(8))) short short8;
typedef __attribute__((ext_vector_type(4))) float floatx4;
typedef __attribute__((ext_vector_type(2))) unsigned int uint2v;

__device__ __forceinline__ unsigned short f2bf(float f) {
  union { float f; unsigned int u; } v; v.f = f;
  unsigned int u = v.u;
  u += 0x7fffu + ((u >> 16) & 1u);
  return (unsigned short)(u >> 16);
}
__device__ __forceinline__ unsigned short f2bf_fast(float f) {
  union { float f; unsigned int u; } v; v.f = f;
  return (unsigned short)((v.u + 0x8000u) >> 16);
}

typedef __attribute__((address_space(1))) const unsigned int as1_u32;
typedef __attribute__((address_space(3))) unsigned int as3_u32;
__device__ __forceinline__ void async16(const void* g, void* l) {
  __builtin_amdgcn_global_load_lds((as1_u32*)g, (as3_u32*)l, 16, 0, 0);
}

// ---------------------------------------------------------------------------
// Split-K c_qkv GEMM (dbuf, BK=32): z=0/1 computes K-half into P0/P1 (fp32,
// no bias — bias added in the reduce). lda/ldb=2048, ldc=1792, all cols valid.
// ---------------------------------------------------------------------------
__global__ __launch_bounds__(256) void gemm_dqkv_sk(
    const unsigned short* __restrict__ A,
    const unsigned short* __restrict__ B,
    float* __restrict__ P0, float* __restrict__ P1)
{
  __shared__ __align__(16) unsigned short sm[16384];
  const int kz = blockIdx.z;
  const unsigned short* Ab = A + kz * 1024;
  const unsigned short* Bb = B + kz * 1024;
  float* C = kz ? P1 : P0;
  const int K = 1024;

  const int tid = threadIdx.x;
  const int w = tid >> 6, lane = tid & 63, q = lane >> 4, r = lane & 15;
  const int bm = blockIdx.y * 128, bn = blockIdx.x * 128;

  floatx4 acc[4][4];
#pragma unroll
  for (int i = 0; i < 4; i++)
#pragma unroll
    for (int j = 0; j < 4; j++) acc[i][j] = (floatx4){0.f, 0.f, 0.f, 0.f};

  const int srow = tid >> 2, scol = (tid & 3) * 8;
  const unsigned short* Ag0 = Ab + (size_t)(bm + srow) * 2048 + scol;
  const unsigned short* Ag1 = Ab + (size_t)(bm + 64 + srow) * 2048 + scol;
  const unsigned short* Bg0 = Bb + (size_t)(bn + srow) * 2048 + scol;
  const unsigned short* Bg1 = Bb + (size_t)(bn + 64 + srow) * 2048 + scol;
  const int mrow0 = (w >> 1) * 64, ncol0 = (w & 1) * 64;

  async16(Ag0, &sm[w * 512]);
  async16(Ag1, &sm[2048 + w * 512]);
  async16(Bg0, &sm[8192 + w * 512]);
  async16(Bg1, &sm[8192 + 2048 + w * 512]);

  for (int k0 = 0; k0 < K; k0 += 32) {
    const int cur = (k0 >> 5) & 1;
    __syncthreads();
    if (k0 + 32 < K) {
      const int nxt = cur ^ 1;
      async16(Ag0 + k0 + 32, &sm[nxt * 4096 + w * 512]);
      async16(Ag1 + k0 + 32, &sm[nxt * 4096 + 2048 + w * 512]);
      async16(Bg0 + k0 + 32, &sm[8192 + nxt * 4096 + w * 512]);
      async16(Bg1 + k0 + 32, &sm[8192 + nxt * 4096 + 2048 + w * 512]);
    }
    const unsigned short* As = &sm[cur * 4096];
    const unsigned short* Bs = &sm[8192 + cur * 4096];
    short8 a[4], b[4];
#pragma unroll
    for (int i = 0; i < 4; i++)
      a[i] = *(const short8*)&As[(mrow0 + i * 16 + r) * 32 + q * 8];
#pragma unroll
    for (int j = 0; j < 4; j++)
      b[j] = *(const short8*)&Bs[(ncol0 + j * 16 + r) * 32 + q * 8];
#pragma unroll
    for (int i = 0; i < 4; i++)
#pragma unroll
      for (int j = 0; j < 4; j++)
        acc[i][j] = __builtin_amdgcn_mfma_f32_16x16x32_bf16(a[i], b[j], acc[i][j], 0, 0, 0);
  }

#pragma unroll
  for (int j = 0; j < 4; j++) {
    int gc = bn + ncol0 + j * 16 + r;
#pragma unroll
    for (int i = 0; i < 4; i++) {
#pragma unroll
      for (int v = 0; v < 4; v++) {
        int gr = bm + mrow0 + i * 16 + q * 4 + v;
        C[(size_t)gr * NQKV + gc] = acc[i][j][v];
      }
    }
  }
}

// ---------------------------------------------------------------------------
// Wo GEMM, BK=64 dbuf (unchanged).
// ---------------------------------------------------------------------------
__global__ __launch_bounds__(256) void gemm_wo64(
    const unsigned short* __restrict__ A,
    const unsigned short* __restrict__ B,
    const float* __restrict__ bias, float* __restrict__ C)
{
  __shared__ __align__(16) unsigned short sm[32768]; // A:2x8192 @0, B:@16384
  const int tid = threadIdx.x;
  const int w = tid >> 6, lane = tid & 63, q = lane >> 4, r = lane & 15;
  const int bm = blockIdx.y * 128, bn = blockIdx.x * 128;

  floatx4 acc[4][4];
#pragma unroll
  for (int i = 0; i < 4; i++)
#pragma unroll
    for (int j = 0; j < 4; j++) acc[i][j] = (floatx4){0.f, 0.f, 0.f, 0.f};

  const int srow = tid >> 2, scol = (tid & 3) * 8;
  const unsigned short* Ag0 = A + (size_t)(bm + srow) * 2048 + scol;
  const unsigned short* Ag1 = A + (size_t)(bm + 64 + srow) * 2048 + scol;
  const unsigned short* Bg0 = B + (size_t)(bn + srow) * 2048 + scol;
  const unsigned short* Bg1 = B + (size_t)(bn + 64 + srow) * 2048 + scol;
  const int mrow0 = (w >> 1) * 64, ncol0 = (w & 1) * 64;

#pragma unroll
  for (int c2 = 0; c2 < 2; c2++) {
    async16(Ag0 + c2 * 32, &sm[c2 * 4096 + w * 512]);
    async16(Ag1 + c2 * 32, &sm[c2 * 4096 + 2048 + w * 512]);
    async16(Bg0 + c2 * 32, &sm[16384 + c2 * 4096 + w * 512]);
    async16(Bg1 + c2 * 32, &sm[16384 + c2 * 4096 + 2048 + w * 512]);
  }

  for (int k0 = 0; k0 < 2048; k0 += 64) {
    const int cur = (k0 >> 6) & 1;
    __syncthreads();
    if (k0 + 64 < 2048) {
      const int nxt = cur ^ 1;
#pragma unroll
      for (int c2 = 0; c2 < 2; c2++) {
        async16(Ag0 + k0 + 64 + c2 * 32, &sm[nxt * 8192 + c2 * 4096 + w * 512]);
        async16(Ag1 + k0 + 64 + c2 * 32, &sm[nxt * 8192 + c2 * 4096 + 2048 + w * 512]);
        async16(Bg0 + k0 + 64 + c2 * 32, &sm[16384 + nxt * 8192 + c2 * 4096 + w * 512]);
        async16(Bg1 + k0 + 64 + c2 * 32, &sm[16384 + nxt * 8192 + c2 * 4096 + 2048 + w * 512]);
      }
    }
#pragma unroll
    for (int c2 = 0; c2 < 2; c2++) {
      const unsigned short* As = &sm[cur * 8192 + c2 * 4096];
      const unsigned short* Bs = &sm[16384 + cur * 8192 + c2 * 4096];
      short8 a[4], b[4];
#pragma unroll
      for (int i = 0; i < 4; i++)
        a[i] = *(const short8*)&As[(mrow0 + i * 16 + r) * 32 + q * 8];
#pragma unroll
      for (int j = 0; j < 4; j++)
        b[j] = *(const short8*)&Bs[(ncol0 + j * 16 + r) * 32 + q * 8];
#pragma unroll
      for (int i = 0; i < 4; i++)
#pragma unroll
        for (int j = 0; j < 4; j++)
          acc[i][j] = __builtin_amdgcn_mfma_f32_16x16x32_bf16(a[i], b[j], acc[i][j], 0, 0, 0);
    }
  }

#pragma unroll
  for (int j = 0; j < 4; j++) {
    int gc = bn + ncol0 + j * 16 + r;
    float bv = bias[gc];
#pragma unroll
    for (int i = 0; i < 4; i++) {
#pragma unroll
      for (int v = 0; v < 4; v++) {
        int gr = bm + mrow0 + i * 16 + q * 4 + v;
        C[(size_t)gr * 2048 + gc] = acc[i][j][v] + bv;
      }
    }
  }
}

// ---------------------------------------------------------------------------
// Fused up-projections. NEW: Kn/V tile writes are column-group XOR-swizzled
// (col ^ ((row>>1)&3)<<3) so attn's ds_read_b128 is bank-conflict-free.
// ---------------------------------------------------------------------------
__global__ __launch_bounds__(256) void gemm_up_fused(
    const unsigned short* __restrict__ Aq, const unsigned short* __restrict__ Bq,
    const float* __restrict__ biasq, unsigned short* __restrict__ Qall,
    const unsigned short* __restrict__ Akv, const unsigned short* __restrict__ Bkv,
    const float* __restrict__ biaskv,
    unsigned short* __restrict__ Kn, unsigned short* __restrict__ Vb)
{
  __shared__ __align__(16) unsigned short sm[16384];
  const int tid = threadIdx.x;
  const int w = tid >> 6, lane = tid & 63, q = lane >> 4, r = lane & 15;
  const int bx = blockIdx.x;
  const bool isQ = bx < 16;
  const int bn = isQ ? bx * 128 : (bx - 16) * 128;
  const int bm = blockIdx.y * 128;
  const int K = isQ ? DQP : DKV;
  const unsigned short* A = isQ ? Aq : Akv;
  const unsigned short* B = isQ ? Bq : Bkv;

  floatx4 acc[4][4];
#pragma unroll
  for (int i = 0; i < 4; i++)
#pragma unroll
    for (int j = 0; j < 4; j++) acc[i][j] = (floatx4){0.f, 0.f, 0.f, 0.f};

  const int srow = tid >> 2, scol = (tid & 3) * 8;
  const unsigned short* Ag0 = A + (size_t)(bm + srow) * K + scol;
  const unsigned short* Ag1 = A + (size_t)(bm + 64 + srow) * K + scol;
  const unsigned short* Bg0 = B + (size_t)(bn + srow) * K + scol;
  const unsigned short* Bg1 = B + (size_t)(bn + 64 + srow) * K + scol;
  const int mrow0 = (w >> 1) * 64, ncol0 = (w & 1) * 64;

  async16(Ag0, &sm[w * 512]);
  async16(Ag1, &sm[2048 + w * 512]);
  async16(Bg0, &sm[8192 + w * 512]);
  async16(Bg1, &sm[8192 + 2048 + w * 512]);

  for (int k0 = 0; k0 < K; k0 += 32) {
    const int cur = (k0 >> 5) & 1;
    __syncthreads();
    if (k0 + 32 < K) {
      const int nxt = cur ^ 1;
      async16(Ag0 + k0 + 32, &sm[nxt * 4096 + w * 512]);
      async16(Ag1 + k0 + 32, &sm[nxt * 4096 + 2048 + w * 512]);
      async16(Bg0 + k0 + 32, &sm[8192 + nxt * 4096 + w * 512]);
      async16(Bg1 + k0 + 32, &sm[8192 + nxt * 4096 + 2048 + w * 512]);
    }
    const unsigned short* As = &sm[cur * 4096];
    const unsigned short* Bs = &sm[8192 + cur * 4096];
    short8 a[4], b[4];
#pragma unroll
    for (int i = 0; i < 4; i++)
      a[i] = *(const short8*)&As[(mrow0 + i * 16 + r) * 32 + q * 8];
#pragma unroll
    for (int j = 0; j < 4; j++)
      b[j] = *(const short8*)&Bs[(ncol0 + j * 16 + r) * 32 + q * 8];
#pragma unroll
    for (int i = 0; i < 4; i++)
#pragma unroll
      for (int j = 0; j < 4; j++)
        acc[i][j] = __builtin_amdgcn_mfma_f32_16x16x32_bf16(a[i], b[j], acc[i][j], 0, 0, 0);
  }

  if (!isQ) {
#pragma unroll
    for (int j = 0; j < 4; j++) {
      int gc = bn + ncol0 + j * 16 + r;
      float bv = biaskv[gc];
      int hh = gc / 192;
      int rel = gc - hh * 192;
#pragma unroll
      for (int i = 0; i < 4; i++) {
#pragma unroll
        for (int v = 0; v < 4; v++) {
          int gr = bm + mrow0 + i * 16 + q * 4 + v;
          int bb = gr >> 11, tt = gr & 2047;
          int bhh = bb * NH + hh;
          int kt = tt >> 6;
          unsigned short val = f2bf(acc[i][j][v] + bv);
          if (rel < 64) {
            // K tile: row = tt&63, col = rel&31, swizzled by row bits 1-2
            Kn[((size_t)(bhh * 32 + kt)) * 4096 + (rel >> 5) * 2048 +
               (tt & 63) * 32 + ((rel & 31) ^ (((tt >> 1) & 3) << 3))] = val;
          } else {
            int d = rel - 64;
            // V tile: row = d, col = tt&31, swizzled by d bits 1-2
            Vb[((size_t)(bhh * 32 + kt)) * 8192 + ((tt >> 5) & 1) * 4096 +
               d * 32 + ((tt & 31) ^ (((d >> 1) & 3) << 3))] = val;
          }
        }
      }
    }
    return;
  }

  const int h = bx;
  const float QS = (float)(0.08838834764831845 * 1.4426950408889634);
  if ((w & 1) == 0) {
#pragma unroll
    for (int j = 0; j < 4; j++) {
      int d = j * 16 + r;
      float bv = biasq[h * 128 + d];
#pragma unroll
      for (int i = 0; i < 4; i++) {
#pragma unroll
        for (int v = 0; v < 4; v++) {
          int gr = bm + mrow0 + i * 16 + q * 4 + v;
          int bb = gr >> 11, t = gr & 2047;
          Qall[(((size_t)(bb * NH + h)) * T_SEQ + t) * 128 + d] =
              f2bf((acc[i][j][v] + bv) * QS);
        }
      }
    }
  } else {
    float cs[2], sn[2], bv1[2], bv2[2];
#pragma unroll
    for (int jp = 0; jp < 2; jp++) {
      int jj = jp * 16 + r;
      float ang = (float)h * exp2f(-(float)jj * (13.287712379549449f / 32.0f));
      cs[jp] = cosf(ang); sn[jp] = sinf(ang);
      bv1[jp] = biasq[h * 128 + 64 + jj];
      bv2[jp] = biasq[h * 128 + 96 + jj];
    }
#pragma unroll
    for (int i = 0; i < 4; i++) {
#pragma unroll
      for (int v = 0; v < 4; v++) {
        int gr = bm + mrow0 + i * 16 + q * 4 + v;
        int bb = gr >> 11, t = gr & 2047;
        unsigned short* Qr = Qall + (((size_t)(bb * NH + h)) * T_SEQ + t) * 128;
#pragma unroll
        for (int jp = 0; jp < 2; jp++) {
          int jj = jp * 16 + r;
          float x1 = acc[i][jp][v] + bv1[jp];
          float x2 = acc[i][jp + 2][v] + bv2[jp];
          Qr[64 + jj] = f2bf((x1 * cs[jp] + x2 * sn[jp]) * QS);
          Qr[96 + jj] = f2bf((x2 * cs[jp] - x1 * sn[jp]) * QS);
        }
      }
    }
  }
}

// ---------------------------------------------------------------------------
// One prep launch: x cvt + 5 weight cvts + bias concat (block-range dispatch).
// ---------------------------------------------------------------------------
__device__ __forceinline__ void cvt_region(
    const float* __restrict__ in, unsigned short* __restrict__ out,
    int irows, int icols, int ocols, long idx)
{
  int rr = (int)(idx / ocols);
  int cc = (int)(idx - (long)rr * ocols);
  out[idx] = (rr < irows && cc < icols) ? f2bf(in[(size_t)rr * icols + cc]) : 0;
}

__global__ __launch_bounds__(256) void prep_all(
    const float* __restrict__ x,
    const float* __restrict__ Wdq_w, const float* __restrict__ Wdkv_w,
    const float* __restrict__ Wuq_w, const float* __restrict__ Wukv_w,
    const float* __restrict__ Wo_w,
    const float* __restrict__ Wdq_b, const float* __restrict__ Wdkv_b,
    unsigned short* __restrict__ x_bf,
    unsigned short* __restrict__ Wqkv_bf, unsigned short* __restrict__ Wuq_bf,
    unsigned short* __restrict__ Wukv_bf, unsigned short* __restrict__ Wo_bf,
    float* __restrict__ bias_qkv)
{
  const long bx = blockIdx.x;
  if (bx < 32768) {
    long idx = bx * 256 + threadIdx.x;
    x_bf[idx] = f2bf(x[idx]);
  } else if (bx < 38400) {
    cvt_region(Wdq_w, Wqkv_bf, 682, 2048, 2048, (bx - 32768) * 256 + threadIdx.x);
  } else if (bx < 47104) {
    cvt_region(Wdkv_w, Wqkv_bf + 704L * 2048, 1088, 2048, 2048,
               (bx - 38400) * 256 + threadIdx.x);
  } else if (bx < 52736) {
    cvt_region(Wuq_w, Wuq_bf, 2048, 682, 704, (bx - 47104) * 256 + threadIdx.x);
  } else if (bx < 65024) {
    cvt_region(Wukv_w, Wukv_bf, 3072, 1024, 1024, (bx - 52736) * 256 + threadIdx.x);
  } else if (bx < 81408) {
    cvt_region(Wo_w, Wo_bf, 2048, 2048, 2048, (bx - 65024) * 256 + threadIdx.x);
  } else {
    int i = (int)(bx - 81408) * 256 + threadIdx.x;
    if (i < NQKV)
      bias_qkv[i] = (i < DQ) ? Wdq_b[i] : ((i < DQP) ? 0.f : Wdkv_b[i - DQP]);
  }
}

// ---------------------------------------------------------------------------
// ln_dual_r: reduce split-K partials + dual LayerNorm. NEW: single read pass
// (values cached in 4 regs/thread, statically indexed); Kr writes swizzled
// to match attn's bank-conflict-free read pattern.
// ---------------------------------------------------------------------------
__global__ __launch_bounds__(256) void ln_dual_r(
    const float* __restrict__ p0, const float* __restrict__ p1,
    const float* __restrict__ bqkv,
    unsigned short* __restrict__ outq, unsigned short* __restrict__ outkv,
    unsigned short* __restrict__ Kr,
    const float* __restrict__ qg, const float* __restrict__ qb2,
    const float* __restrict__ kg, const float* __restrict__ kb2)
{
  __shared__ float sbuf[8];
  const int blk = blockIdx.x;
  if (blk >= 8192) {
    const int base = (blk - 8192) * 512;
#pragma unroll
    for (int s = 0; s < 2; s++) {
      int idx = base + s * 256 + threadIdx.x;
      int row = idx >> 6, dr = idx & 63;
      size_t off = (size_t)row * NQKV + 1728 + dr;
      float v = p0[off] + p1[off] + bqkv[1728 + dr];
      Kr[((size_t)((row >> 11) * 32 + ((row & 2047) >> 6))) * 4096 +
         (dr >> 5) * 2048 + (row & 63) * 32 +
         ((dr & 31) ^ (((row >> 1) & 3) << 3))] = f2bf(v);
    }
    return;
  }
  const bool isQ = blk < 4096;
  const int r2 = isQ ? blk : blk - 4096;
  const int off = isQ ? 0 : DQP;
  const float* x0 = p0 + (size_t)r2 * NQKV + off;
  const float* x1 = p1 + (size_t)r2 * NQKV + off;
  const float* bb = bqkv + off;
  const int D = isQ ? DQ : DKV;
  const int ocols = isQ ? DQP : DKV;
  const float* g = isQ ? qg : kg;
  const float* bta = isQ ? qb2 : kb2;
  unsigned short* orow = (isQ ? outq : outkv) + (size_t)r2 * ocols;

  float s = 0.f, s2 = 0.f;
  float vv[4];
#pragma unroll
  for (int ii = 0; ii < 4; ii++) {
    int i = threadIdx.x + ii * 256;
    if (i < D) {
      float v = x0[i] + x1[i] + bb[i];
      vv[ii] = v;
      s += v; s2 += v * v;
    }
  }
#pragma unroll
  for (int o = 32; o > 0; o >>= 1) {
    s += __shfl_down(s, o, 64);
    s2 += __shfl_down(s2, o, 64);
  }
  int wid = threadIdx.x >> 6;
  __syncthreads();
  if ((threadIdx.x & 63) == 0) { sbuf[wid] = s; sbuf[4 + wid] = s2; }
  __syncthreads();
  float su = sbuf[0] + sbuf[1] + sbuf[2] + sbuf[3];
  float sq = sbuf[4] + sbuf[5] + sbuf[6] + sbuf[7];
  float mu = su / (float)D;
  float var = sq / (float)D - mu * mu;
  float rstd = rsqrtf(var + 1e-5f);
#pragma unroll
  for (int ii = 0; ii < 4; ii++) {
    int i = threadIdx.x + ii * 256;
    if (i < ocols)
      orow[i] = (i < D) ? f2bf((vv[ii] - mu) * rstd * g[i] + bta[i]) : 0;
  }
}

// ---------------------------------------------------------------------------
// attn v6: balanced-pair flash attention (33 its/block) +
//  - swizzled K/V LDS reads (sq8 = (q ^ ((r>>1)&3))*8) — conflict-free b128
//  - tree-reduced fmax/sum (depth 4 instead of 15-op serial chain)
//  - defer-max (skip O-rescale when tile max grows <= 8 in log2 units)
//  - s_setprio(1) around MFMA clusters
// ---------------------------------------------------------------------------
__global__ __launch_bounds__(256, 2) void attn_mfma6(
    const unsigned short* __restrict__ Qall,
    const unsigned short* __restrict__ Kn,
    const unsigned short* __restrict__ Kr,
    const unsigned short* __restrict__ Vb,
    unsigned short* __restrict__ y)
{
  __shared__ __align__(16) unsigned short sm[37376];
  const int id = (int)blockIdx.x;
  const int bhid = id & 31;
  const int pr = id >> 5;           // 0..15 : pair index
  const int h = bhid & 15, b = bhid >> 4;
  const int tid = threadIdx.x;
  const int w = tid >> 6, lane = tid & 63, q = lane >> 4, r = lane & 15;
  const int bh = bhid;
  const int sq8 = (q ^ ((r >> 1) & 3)) * 8;   // swizzled col-group for K/V reads

  const char* KnG = (const char*)(Kn + (size_t)bh * 32 * 4096);
  const char* KrG = (const char*)(Kr + (size_t)b * 32 * 4096);
  const char* VG  = (const char*)(Vb + (size_t)bh * 32 * 8192);
  char* smB = (char*)sm;
  unsigned short* Psw = sm + 32768 + w * 1152;

#define PREFETCH_KV(kt_, buf_)                                                 \
  {                                                                            \
    const char* kn_ = KnG + (size_t)(kt_) * 8192;                              \
    const char* kr_ = KrG + (size_t)(kt_) * 8192;                              \
    const char* vg_ = VG + (size_t)(kt_) * 16384;                              \
    char* kd_ = smB + (buf_) * 16384;                                          \
    char* vd_ = smB + 32768 + (buf_) * 16384;                                  \
    _Pragma("unroll")                                                          \
    for (int i_ = 0; i_ < 2; i_++) {                                           \
      async16(kn_ + i_ * 4096 + w * 1024 + lane * 16,                          \
              kd_ + i_ * 4096 + w * 1024);                                     \
      async16(kr_ + i_ * 4096 + w * 1024 + lane * 16,                          \
              kd_ + 8192 + i_ * 4096 + w * 1024);                              \
    }                                                                          \
    _Pragma("unroll")                                                          \
    for (int i_ = 0; i_ < 4; i_++)                                             \
      async16(vg_ + i_ * 4096 + w * 1024 + lane * 16,                          \
              vd_ + i_ * 4096 + w * 1024);                                     \
  }

  for (int seg = 0; seg < 2; seg++) {
    const int a = seg ? (31 - pr) : pr;   // q-tile index, rows [a*64, a*64+64)
    if (seg) __syncthreads();             // all reads of prev segment done
    PREFETCH_KV(0, 0);

    // Q fragment for this wave's 16 rows: [a*64 + w*16 + r]
    short8 qb[4];
    const unsigned short* Qrow =
        Qall + ((size_t)bh * T_SEQ + (size_t)a * 64 + w * 16 + r) * 128 + q * 8;
#pragma unroll
    for (int c = 0; c < 4; c++) qb[c] = *(const short8*)(Qrow + c * 32);

    floatx4 oacc[8];
#pragma unroll
    for (int jd = 0; jd < 8; jd++) oacc[jd] = (floatx4){0.f, 0.f, 0.f, 0.f};
    float m_i = -3.0e38f, l_i = 0.f;

    for (int kt = 0; kt <= a; kt++) {
      const int cur = kt & 1;
      __syncthreads();
      if (kt < a) PREFETCH_KV(kt + 1, cur ^ 1);

      const unsigned short* KsC = sm + cur * 8192;
      const unsigned short* VsC = sm + 16384 + cur * 8192;

      floatx4 sacc[4];
#pragma unroll
      for (int j = 0; j < 4; j++) sacc[j] = (floatx4){0.f, 0.f, 0.f, 0.f};
      __builtin_amdgcn_s_setprio(1);
#pragma unroll
      for (int c = 0; c < 4; c++) {
        short8 ak[4];
#pragma unroll
        for (int j = 0; j < 4; j++)
          ak[j] = *(const short8*)&KsC[c * 2048 + (j * 16 + r) * 32 + sq8];
#pragma unroll
        for (int j = 0; j < 4; j++)
          sacc[j] = __builtin_amdgcn_mfma_f32_16x16x32_bf16(ak[j], qb[c], sacc[j], 0, 0, 0);
      }
      __builtin_amdgcn_s_setprio(0);

      float sv[16];
#pragma unroll
      for (int j = 0; j < 4; j++)
#pragma unroll
        for (int v = 0; v < 4; v++) sv[j * 4 + v] = sacc[j][v];
      const int rel = (a - kt) * 64 + w * 16 + r;
      if (rel < 63) {
#pragma unroll
        for (int j = 0; j < 4; j++)
#pragma unroll
          for (int v = 0; v < 4; v++)
            if (j * 16 + q * 4 + v > rel) sv[j * 4 + v] = -3.0e38f;
      }
      // tree-reduce max (depth 4)
      float tm[8];
#pragma unroll
      for (int t = 0; t < 8; t++) tm[t] = fmaxf(sv[t], sv[t + 8]);
#pragma unroll
      for (int t = 0; t < 4; t++) tm[t] = fmaxf(tm[t], tm[t + 4]);
      float rm = fmaxf(fmaxf(tm[0], tm[2]), fmaxf(tm[1], tm[3]));
      rm = fmaxf(rm, __shfl_xor(rm, 16, 64));
      rm = fmaxf(rm, __shfl_xor(rm, 32, 64));
      // defer-max: rescale only if tile max grew > 8 (log2 units)
      if (__any(rm > m_i + 8.f)) {
        float mnew = fmaxf(m_i, rm);
        float alpha = exp2f(m_i - mnew);
        m_i = mnew;
        l_i *= alpha;
#pragma unroll
        for (int jd = 0; jd < 8; jd++) {
          oacc[jd][0] *= alpha; oacc[jd][1] *= alpha;
          oacc[jd][2] *= alpha; oacc[jd][3] *= alpha;
        }
      }
      float p[16];
#pragma unroll
      for (int t = 0; t < 16; t++) p[t] = exp2f(sv[t] - m_i);
      // tree-reduce sum (depth 4)
      float ts[8];
#pragma unroll
      for (int t = 0; t < 8; t++) ts[t] = p[t] + p[t + 8];
#pragma unroll
      for (int t = 0; t < 4; t++) ts[t] = ts[t] + ts[t + 4];
      float rsum = (ts[0] + ts[2]) + (ts[1] + ts[3]);
      rsum += __shfl_xor(rsum, 16, 64);
      rsum += __shfl_xor(rsum, 32, 64);
      l_i += rsum;
#pragma unroll
      for (int j = 0; j < 4; j++) {
        unsigned int lo = (unsigned int)f2bf_fast(p[j * 4 + 0]) |
                          ((unsigned int)f2bf_fast(p[j * 4 + 1]) << 16);
        unsigned int hi = (unsigned int)f2bf_fast(p[j * 4 + 2]) |
                          ((unsigned int)f2bf_fast(p[j * 4 + 3]) << 16);
        uint2v pk; pk[0] = lo; pk[1] = hi;
        *(uint2v*)&Psw[r * 72 + j * 16 + q * 4] = pk;
      }
      __builtin_amdgcn_s_setprio(1);
#pragma unroll
      for (int c2 = 0; c2 < 2; c2++) {
        short8 pb = *(const short8*)&Psw[r * 72 + c2 * 32 + q * 8];
#pragma unroll
        for (int jd = 0; jd < 8; jd++) {
          short8 bv = *(const short8*)&VsC[c2 * 4096 + (jd * 16 + r) * 32 + sq8];
          oacc[jd] = __builtin_amdgcn_mfma_f32_16x16x32_bf16(bv, pb, oacc[jd], 0, 0, 0);
        }
      }
      __builtin_amdgcn_s_setprio(0);
    }

    float inv = 1.0f / l_i;
    unsigned short* yr =
        y + ((size_t)(b * T_SEQ) + (size_t)a * 64 + w * 16 + r) * DM + h * 128;
#pragma unroll
    for (int jd = 0; jd < 8; jd++) {
      unsigned short o0 = f2bf(oacc[jd][0] * inv);
      unsigned short o1 = f2bf(oacc[jd][1] * inv);
      unsigned short o2 = f2bf(oacc[jd][2] * inv);
      unsigned short o3 = f2bf(oacc[jd][3] * inv);
      unsigned int lo = (unsigned int)o0 | ((unsigned int)o1 << 16);
      unsigned int hi = (unsigned int)o2 | ((unsigned int)o3 << 16);
      unsigned int* dst = (unsigned int*)(yr + jd * 16 + q * 4);
      dst[0] = lo; dst[1] = hi;
    }
  }
#undef PREFETCH_KV
}

// ---------------------------------------------------------------------------
extern "C" void kernel_launch(void* const* d_in, const int* in_sizes, int n_in,
                              void* d_out, int out_size, void* d_ws, size_t ws_size,
                              hipStream_t stream) {
  const float* x      = (const float*)d_in[0];
  const float* Wdq_w  = (const float*)d_in[1];
  const float* Wdq_b  = (const float*)d_in[2];
  const float* qn_g   = (const float*)d_in[3];
  const float* qn_b   = (const float*)d_in[4];
  const float* Wuq_w  = (const float*)d_in[5];
  const float* Wuq_b  = (const float*)d_in[6];
  const float* Wdkv_w = (const float*)d_in[7];
  const float* Wdkv_b = (const float*)d_in[8];
  const float* kvn_g  = (const float*)d_in[9];
  const float* kvn_b  = (const float*)d_in[10];
  const float* Wukv_w = (const float*)d_in[11];
  const float* Wukv_b = (const float*)d_in[12];
  const float* Wo_w   = (const float*)d_in[13];
  const float* Wo_b   = (const float*)d_in[14];
  float* out = (float*)d_out;

  float* ws = (float*)d_ws;
  unsigned short* x_bf    = (unsigned short*)(ws);              // dies after dqkv gemm
  unsigned short* y_bf    = (unsigned short*)(ws);              // alias: attn output
  unsigned short* Wqkv_bf = (unsigned short*)(ws + 4194304);    // 1792x2048
  unsigned short* Wuq_bf  = (unsigned short*)(ws + 6029312);    // 2048x704
  unsigned short* Wukv_bf = (unsigned short*)(ws + 6750208);    // 3072x1024
  float* bias_qkv = ws + 8323072;                               // 1792
  float* p0       = ws + 8324864;                               // 4096x1792 fp32
  float* p1       = ws + 15664896;                              // 4096x1792 fp32
  unsigned short* c_q_bf = (unsigned short*)(ws + 23004928);    // 4096x704
  unsigned short* kvn_bf = (unsigned short*)(ws + 24446720);    // 4096x1024
  unsigned short* Q_all  = (unsigned short*)(ws + 26543872);    // 2x16x2048x128
  unsigned short* Kn_blk = (unsigned short*)(ws + 30738176);    // 32bh x 32kt x 4096
  unsigned short* Kr_blk = (unsigned short*)(ws + 32835328);    // 2b x 32kt x 4096
  unsigned short* V_blk  = (unsigned short*)(ws + 32966400);    // 32bh x 32kt x 8192
  unsigned short* Wo_bf  = (unsigned short*)(ws + 37160704);    // 2048x2048

  dim3 blk(256);

  // one prep launch: x cvt + weights + bias concat
  prep_all<<<81415, blk, 0, stream>>>(x, Wdq_w, Wdkv_w, Wuq_w, Wukv_w, Wo_w,
                                      Wdq_b, Wdkv_b,
                                      x_bf, Wqkv_bf, Wuq_bf, Wukv_bf, Wo_bf,
                                      bias_qkv);
  // split-K c_qkv partials (896 blocks)
  gemm_dqkv_sk<<<dim3(14, 32, 2), blk, 0, stream>>>(x_bf, Wqkv_bf, p0, p1);
  // reduce + dual LN + rope->Kr_blk (swizzled)
  ln_dual_r<<<8704, blk, 0, stream>>>(p0, p1, bias_qkv, c_q_bf, kvn_bf, Kr_blk,
                                      qn_g, qn_b, kvn_g, kvn_b);
  // fused up-projections: qrope -> Q_all ; kv -> Kn_blk / V_blk (swizzled)
  gemm_up_fused<<<dim3(40, 32), blk, 0, stream>>>(c_q_bf, Wuq_bf, Wuq_b, Q_all,
                                                  kvn_bf, Wukv_bf, Wukv_b,
                                                  Kn_blk, V_blk);
  // attention: balanced-pair schedule + swizzle + defer-max + setprio
  attn_mfma6<<<512, blk, 0, stream>>>(Q_all, Kn_blk, Kr_blk, V_blk, y_bf);
  // out = y @ Wo^T + b (BK=64 dbuf)
  gemm_wo64<<<dim3(16, 32), blk, 0, stream>>>(y_bf, Wo_bf, Wo_b, out);
}